// Round 4
// baseline (139.209 us; speedup 1.0000x reference)
//
#include <hip/hip_runtime.h>

#define BATCH  2048
#define TLEN   128
#define CH     5
#define NSTEP  127
#define HALF1  64                 // L segment steps; R segment = 63 real + 1 zero pad
#define SIGDIM 780                // 5 + 25 + 125 + 625
#define KACC   16                 // global accumulator copies
#define NBLK   2048               // 2 paths per block, 4 waves (2 segs x 2 paths)

// Block = 4 waves = 2 paths x 2 time-halves. Each wave computes the depth-4
// signature of its 64-step segment (one wave-step: 2 LDS reads + ~45 VALU,
// no barriers). Lane pair l,l+1 owns level-2 chain ab=l>>1 (redundant track);
// even lane owns level-3 prefixes c in {0,1,2}, odd c in {3,4}, each with 5
// level-4 accumulators in registers. Segment sigs -> LDS, Chen-combined
// in-block (S = SL (x) SR), then signed global atomics; last block reduces.
__global__ __launch_bounds__(256, 8) void sig_kernel(
    const float* __restrict__ x, const float* __restrict__ y,
    const float* __restrict__ sigma, float* __restrict__ acc,
    unsigned int* __restrict__ counter, float* __restrict__ out) {
  const int tid  = threadIdx.x;
  const int wave = tid >> 6;
  const int lane = tid & 63;
  const bool isX = (blockIdx.x < NBLK / 2);
  const int pbase = isX ? 2 * blockIdx.x : 2 * (blockIdx.x - NBLK / 2);
  const int path  = pbase + (wave >> 1);
  const int seg   = wave & 1;

  // per-wave buffer: increments (rows t*8, t<65) overlaid later by segment sig (780)
  __shared__ __align__(16) float wbuf[4][784];
  __shared__ float blockAcc[SIGDIM];
  __shared__ float red[4];
  __shared__ unsigned int lastFlag;

  // ---- fill increments ----
  float* dxw = wbuf[wave];
  if (lane < 16) dxw[504 + lane] = 0.f;          // zero rows 63,64 (pad + prefetch slack)
  {
    const float* src = (isX ? x : y) + (size_t)path * (TLEN * CH) + seg * (HALF1 * CH);
    const int lim = seg ? (63 * CH) : (64 * CH);
    for (int i = lane; i < lim; i += 64) {
      int t = i / CH, c = i - CH * t;
      float v = src[i + CH] - src[i];
      if (isX && c > 0) v *= sigma[c - 1];
      dxw[t * 8 + c] = v;
    }
  }
  __syncthreads();

  // ---- per-lane ownership ----
  const int  ab  = (lane >> 1) < 25 ? (lane >> 1) : 24;   // clamp idle lanes 50..63
  const int  a_  = ab / 5, b_ = ab - 5 * a_;
  const bool odd = (lane & 1);
  const int  c0i = odd ? 3 : 0, c1i = odd ? 4 : 1;
  const bool act = (lane < 50);

  float s1a = 0.f, s2 = 0.f;
  float s30 = 0.f, s31 = 0.f, s32 = 0.f;
  float s40[5] = {0,0,0,0,0}, s41[5] = {0,0,0,0,0}, s42[5] = {0,0,0,0,0};

  #pragma unroll 4
  for (int t = 0; t < HALF1; ++t) {              // R segment's row 63 is zero -> no-op
    const float* row = dxw + t * 8;
    const float4 dv = *(const float4*)row;
    const float d0 = dv.x, d1 = dv.y, d2 = dv.z, d3 = dv.w;
    const float d4 = row[4];
    const float da  = a_ == 0 ? d0 : a_ == 1 ? d1 : a_ == 2 ? d2 : a_ == 3 ? d3 : d4;
    const float db  = b_ == 0 ? d0 : b_ == 1 ? d1 : b_ == 2 ? d2 : b_ == 3 ? d3 : d4;
    const float dc0 = odd ? d3 : d0;
    const float dc1 = odd ? d4 : d1;
    // level-1 chain (old s1a)
    const float pa = s1a * (1.f / 6.f) + da * (1.f / 24.f);
    const float qa = s1a * 0.5f        + da * (1.f / 6.f);
    const float ra = s1a               + da * 0.5f;
    s1a += da;
    // level-2 chain (old s2)
    const float p2 = 0.5f * s2 + db * pa;
    const float q2 =        s2 + db * qa;
    s2 += db * ra;
    // level-3/4 (old s3)
    const float p30 = s30 + dc0 * p2;  s30 += dc0 * q2;
    const float p31 = s31 + dc1 * p2;  s31 += dc1 * q2;
    const float p32 = s32 + d2  * p2;  s32 += d2  * q2;
    s40[0] += d0 * p30; s40[1] += d1 * p30; s40[2] += d2 * p30; s40[3] += d3 * p30; s40[4] += d4 * p30;
    s41[0] += d0 * p31; s41[1] += d1 * p31; s41[2] += d2 * p31; s41[3] += d3 * p31; s41[4] += d4 * p31;
    s42[0] += d0 * p32; s42[1] += d1 * p32; s42[2] += d2 * p32; s42[3] += d3 * p32; s42[4] += d4 * p32;
  }

  // ---- publish segment signature into own wbuf (increments are dead) ----
  {
    float* sg = wbuf[wave];
    if (act) {
      if ((lane % 10) == 0) sg[lane / 10] = s1a;        // L1[a]
      if (!odd)             sg[5 + ab]    = s2;         // L2[ab]
      const int base3 = 30 + ab * 5;
      sg[base3 + c0i] = s30;
      sg[base3 + c1i] = s31;
      if (!odd) sg[base3 + 2] = s32;
      const int b40 = 155 + (ab * 5 + c0i) * 5;
      const int b41 = 155 + (ab * 5 + c1i) * 5;
      const int b42 = 155 + (ab * 5 + 2) * 5;
      #pragma unroll
      for (int d = 0; d < 5; ++d) sg[b40 + d] = s40[d];
      #pragma unroll
      for (int d = 0; d < 5; ++d) sg[b41 + d] = s41[d];
      if (!odd) {
        #pragma unroll
        for (int d = 0; d < 5; ++d) sg[b42 + d] = s42[d];
      }
    }
  }
  __syncthreads();

  // ---- Chen combine S = SL (x) SR per path; threads 0..127 path A, 128..255 path B
  const int half = tid >> 7;
  const int t2   = tid & 127;
  const float* L = wbuf[2 * half];
  const float* R = wbuf[2 * half + 1];
  float o4[5] = {0,0,0,0,0};
  float o3 = 0.f, o2 = 0.f, o1 = 0.f;
  if (t2 < 125) {
    const int abc = t2, abq = abc / 5, c = abc - 5 * abq;
    const int a = abq / 5, b = abq - 5 * a;
    const float l1 = L[a], l2 = L[5 + abq], l3 = L[30 + abc];
    o3 = l3 + R[30 + abc] + l2 * R[c] + l1 * R[5 + b * 5 + c];
    #pragma unroll
    for (int d = 0; d < 5; ++d)
      o4[d] = L[155 + abc * 5 + d] + R[155 + abc * 5 + d]
            + l3 * R[d] + l2 * R[5 + c * 5 + d] + l1 * R[30 + (b * 5 + c) * 5 + d];
    if (abc < 25) o2 = L[5 + abc] + R[5 + abc] + L[abc / 5] * R[abc - 5 * (abc / 5)];
    if (abc < 5)  o1 = L[abc] + R[abc];
  }
  if (half == 0 && t2 < 125) {
    blockAcc[30 + t2] = o3;
    #pragma unroll
    for (int d = 0; d < 5; ++d) blockAcc[155 + t2 * 5 + d] = o4[d];
    if (t2 < 25) blockAcc[5 + t2] = o2;
    if (t2 < 5)  blockAcc[t2] = o1;
  }
  __syncthreads();
  if (half == 1 && t2 < 125) {
    blockAcc[30 + t2] += o3;
    #pragma unroll
    for (int d = 0; d < 5; ++d) blockAcc[155 + t2 * 5 + d] += o4[d];
    if (t2 < 25) blockAcc[5 + t2] += o2;
    if (t2 < 5)  blockAcc[t2] += o1;
  }
  __syncthreads();

  // ---- signed block -> global ----
  const float w = isX ? 1.0f : -1.0f;
  float* ap = acc + (size_t)(blockIdx.x & (KACC - 1)) * SIGDIM;
  for (int i = tid; i < SIGDIM; i += 256)
    atomicAdd(ap + i, w * blockAcc[i]);

  // ---- fused final reduction: last block computes ||u-v||^2 / B^2 ----
  __syncthreads();
  if (tid == 0) {
    __threadfence();
    unsigned int old = __hip_atomic_fetch_add(counter, 1u, __ATOMIC_ACQ_REL,
                                              __HIP_MEMORY_SCOPE_AGENT);
    lastFlag = (old == NBLK - 1) ? 1u : 0u;
  }
  __syncthreads();
  if (lastFlag) {
    float local = 0.f;
    for (int i = tid; i < SIGDIM; i += 256) {
      float v = 0.f;
      #pragma unroll
      for (int k = 0; k < KACC; ++k)
        v += __hip_atomic_load(&acc[(size_t)k * SIGDIM + i],
                               __ATOMIC_RELAXED, __HIP_MEMORY_SCOPE_AGENT);
      local += v * v;
    }
    #pragma unroll
    for (int off = 32; off > 0; off >>= 1) local += __shfl_down(local, off, 64);
    if ((tid & 63) == 0) red[tid >> 6] = local;
    __syncthreads();
    if (tid == 0)
      out[0] = (red[0] + red[1] + red[2] + red[3]) / (2048.0f * 2048.0f);
  }
}

extern "C" void kernel_launch(void* const* d_in, const int* in_sizes, int n_in,
                              void* d_out, int out_size, void* d_ws, size_t ws_size,
                              hipStream_t stream) {
  const float* x     = (const float*)d_in[0];
  const float* y     = (const float*)d_in[1];
  const float* sigma = (const float*)d_in[2];
  float* out = (float*)d_out;
  float* acc = (float*)d_ws;
  unsigned int* counter = (unsigned int*)((char*)d_ws + (size_t)KACC * SIGDIM * sizeof(float));

  hipMemsetAsync(d_ws, 0, (size_t)KACC * SIGDIM * sizeof(float) + 64, stream);
  sig_kernel<<<dim3(NBLK), dim3(256), 0, stream>>>(x, y, sigma, acc, counter, out);
}

// Round 5
// 138.234 us; speedup vs baseline: 1.0071x; 1.0071x over previous
//
#include <hip/hip_runtime.h>

#define BATCH  2048
#define TLEN   128
#define CH     5
#define NSTEP  127
#define NPAD   132               // 127 real steps + zero pad rows (no-op steps / prefetch slack)
#define SIGDIM 780               // 5 + 25 + 125 + 625
#define KACC   16                // global accumulator copies
#define WPB    4                 // waves (= paths) per block
#define NBLK   ((2 * BATCH) / WPB)   // 1024

// One wave per path, 4 paths per 256-thread block (R3 structure: best measured).
// Increments repacked: main4[t][0..3] (16B rows) + aux[t] (=dx[t][4], contiguous)
// so a 4-step group costs 5 ds_read_b128 total (1.25 LDS ops/step, was 6).
// Channel selects are loop-invariant-mask cndmasks (VALU). 2-deep group pipeline:
// next group's 5 float4 loads issue before current group's 4 steps compute.
__global__ __launch_bounds__(256, 4) void sig_kernel(
    const float* __restrict__ x, const float* __restrict__ y,
    const float* __restrict__ sigma, float* __restrict__ acc,
    unsigned int* __restrict__ counter, float* __restrict__ out) {
  const int tid  = threadIdx.x;
  const int wave = tid >> 6;
  const int lane = tid & 63;
  const int b    = blockIdx.x * WPB + wave;        // sign block-uniform (BATCH%WPB==0)
  const bool isX = (b < BATCH);
  const int  p   = isX ? b : b - BATCH;
  const float* src = (isX ? x : y) + (size_t)p * (TLEN * CH);

  __shared__ __align__(16) float main4[WPB][NPAD * 4]; // d0..d3 per step
  __shared__ __align__(16) float aux  [WPB][NPAD];     // d4 per step
  __shared__ float blockAcc[SIGDIM];
  __shared__ float red[4];
  __shared__ unsigned int lastFlag;

  for (int i = tid; i < SIGDIM; i += 256) blockAcc[i] = 0.f;

  // ---- fill increments (sigma folds linearly into x's non-time channels) ----
  float* mw = main4[wave];
  float* aw = aux[wave];
  if (lane < 20) mw[NSTEP * 4 + lane] = 0.f;   // zero pad rows 127..131
  if (lane < 5)  aw[NSTEP + lane]     = 0.f;
  for (int i = lane; i < NSTEP * CH; i += 64) {
    int t = i / CH, c = i - CH * t;
    float v = src[i + CH] - src[i];
    if (isX && c > 0) v *= sigma[c - 1];
    if (c < 4) mw[t * 4 + c] = v; else aw[t] = v;
  }
  __syncthreads();

  // ---- per-lane ownership (loop-invariant) ----
  const int  ab  = (lane >> 1) < 25 ? (lane >> 1) : 24;  // clamp idle lanes 50..63
  const int  a_  = ab / 5, b_ = ab - 5 * a_;
  const bool odd = (lane & 1);
  const int  c0i = odd ? 3 : 0, c1i = odd ? 4 : 1;
  const bool act = (lane < 50);

  float s1a = 0.f, s2 = 0.f;
  float s30 = 0.f, s31 = 0.f, s32 = 0.f;
  float s40[5] = {0,0,0,0,0}, s41[5] = {0,0,0,0,0}, s42[5] = {0,0,0,0,0};

  auto STEP = [&](float d0, float d1, float d2, float d3, float d4) {
    const float da  = a_ == 0 ? d0 : a_ == 1 ? d1 : a_ == 2 ? d2 : a_ == 3 ? d3 : d4;
    const float db  = b_ == 0 ? d0 : b_ == 1 ? d1 : b_ == 2 ? d2 : b_ == 3 ? d3 : d4;
    const float dc0 = odd ? d3 : d0;
    const float dc1 = odd ? d4 : d1;
    const float pa = s1a * (1.f / 6.f) + da * (1.f / 24.f);
    const float qa = s1a * 0.5f        + da * (1.f / 6.f);
    const float ra = s1a               + da * 0.5f;
    s1a += da;
    const float p2 = 0.5f * s2 + db * pa;
    const float q2 =        s2 + db * qa;
    s2 += db * ra;
    const float p30 = s30 + dc0 * p2;  s30 += dc0 * q2;
    const float p31 = s31 + dc1 * p2;  s31 += dc1 * q2;
    const float p32 = s32 + d2  * p2;  s32 += d2  * q2;
    s40[0] += d0 * p30; s40[1] += d1 * p30; s40[2] += d2 * p30; s40[3] += d3 * p30; s40[4] += d4 * p30;
    s41[0] += d0 * p31; s41[1] += d1 * p31; s41[2] += d2 * p31; s41[3] += d3 * p31; s41[4] += d4 * p31;
    s42[0] += d0 * p32; s42[1] += d1 * p32; s42[2] += d2 * p32; s42[3] += d3 * p32; s42[4] += d4 * p32;
  };

  // ---- main loop: 32 groups of 4 steps (step 127 is a zero no-op) ----
  float4 m0 = *(const float4*)(mw + 0);
  float4 m1 = *(const float4*)(mw + 4);
  float4 m2 = *(const float4*)(mw + 8);
  float4 m3 = *(const float4*)(mw + 12);
  float4 a4 = *(const float4*)(aw + 0);
  for (int blk = 0; blk < 32; ++blk) {
    const float4 cm0 = m0, cm1 = m1, cm2 = m2, cm3 = m3, ca = a4;
    const float* mb = mw + (blk + 1) * 16;   // prefetch next group (pads make overrun safe)
    const float* ab4 = aw + (blk + 1) * 4;
    m0 = *(const float4*)(mb + 0);
    m1 = *(const float4*)(mb + 4);
    m2 = *(const float4*)(mb + 8);
    m3 = *(const float4*)(mb + 12);
    a4 = *(const float4*)(ab4);
    STEP(cm0.x, cm0.y, cm0.z, cm0.w, ca.x);
    STEP(cm1.x, cm1.y, cm1.z, cm1.w, ca.y);
    STEP(cm2.x, cm2.y, cm2.z, cm2.w, ca.z);
    STEP(cm3.x, cm3.y, cm3.z, cm3.w, ca.w);
  }

  // ---- block-local accumulation in LDS ----
  if (act) {
    const int base3 = 30 + ab * 5;
    if ((lane % 10) == 0) atomicAdd(&blockAcc[lane / 10], s1a);
    if (!odd)             atomicAdd(&blockAcc[5 + ab], s2);
    atomicAdd(&blockAcc[base3 + c0i], s30);
    atomicAdd(&blockAcc[base3 + c1i], s31);
    if (!odd) atomicAdd(&blockAcc[base3 + 2], s32);
    const int b40 = 155 + (ab * 5 + c0i) * 5;
    const int b41 = 155 + (ab * 5 + c1i) * 5;
    const int b42 = 155 + (ab * 5 + 2) * 5;
    #pragma unroll
    for (int d = 0; d < 5; ++d) atomicAdd(&blockAcc[b40 + d], s40[d]);
    #pragma unroll
    for (int d = 0; d < 5; ++d) atomicAdd(&blockAcc[b41 + d], s41[d]);
    if (!odd) {
      #pragma unroll
      for (int d = 0; d < 5; ++d) atomicAdd(&blockAcc[b42 + d], s42[d]);
    }
  }
  __syncthreads();

  // ---- signed block -> global ----
  const float w = isX ? 1.0f : -1.0f;
  float* ap = acc + (size_t)(blockIdx.x & (KACC - 1)) * SIGDIM;
  for (int i = tid; i < SIGDIM; i += 256)
    atomicAdd(ap + i, w * blockAcc[i]);

  // ---- fused final reduction: last block computes ||u-v||^2 / B^2 ----
  __syncthreads();
  if (tid == 0) {
    __threadfence();
    unsigned int old = __hip_atomic_fetch_add(counter, 1u, __ATOMIC_ACQ_REL,
                                              __HIP_MEMORY_SCOPE_AGENT);
    lastFlag = (old == NBLK - 1) ? 1u : 0u;
  }
  __syncthreads();
  if (lastFlag) {
    float local = 0.f;
    for (int i = tid; i < SIGDIM; i += 256) {
      float v = 0.f;
      #pragma unroll
      for (int k = 0; k < KACC; ++k)
        v += __hip_atomic_load(&acc[(size_t)k * SIGDIM + i],
                               __ATOMIC_RELAXED, __HIP_MEMORY_SCOPE_AGENT);
      local += v * v;
    }
    #pragma unroll
    for (int off = 32; off > 0; off >>= 1) local += __shfl_down(local, off, 64);
    if ((tid & 63) == 0) red[tid >> 6] = local;
    __syncthreads();
    if (tid == 0)
      out[0] = (red[0] + red[1] + red[2] + red[3]) / (2048.0f * 2048.0f);
  }
}

extern "C" void kernel_launch(void* const* d_in, const int* in_sizes, int n_in,
                              void* d_out, int out_size, void* d_ws, size_t ws_size,
                              hipStream_t stream) {
  const float* x     = (const float*)d_in[0];
  const float* y     = (const float*)d_in[1];
  const float* sigma = (const float*)d_in[2];
  float* out = (float*)d_out;
  float* acc = (float*)d_ws;
  unsigned int* counter = (unsigned int*)((char*)d_ws + (size_t)KACC * SIGDIM * sizeof(float));

  hipMemsetAsync(d_ws, 0, (size_t)KACC * SIGDIM * sizeof(float) + 64, stream);
  sig_kernel<<<dim3(NBLK), dim3(256), 0, stream>>>(x, y, sigma, acc, counter, out);
}

// Round 6
// 123.464 us; speedup vs baseline: 1.1275x; 1.1196x over previous
//
#include <hip/hip_runtime.h>

#define BATCH  2048
#define TLEN   128
#define CH     5
#define NSTEP  127
#define NROW   128               // rows 0..126 real increments, row 127 = zeros (pipeline pad)
#define SIGDIM 780               // 5 + 25 + 125 + 625
#define KACC   16                // global accumulator copies
#define WPB    4                 // waves (= paths) per block
#define NBLK   ((2 * BATCH) / WPB)   // 1024

// R3 structure (best measured: 65 us) + true 2-deep register double-buffer.
// One wave per path, 4 paths per 256-thread block. Lane pair l,l+1 owns
// level-2 chain ab=l>>1; even lane owns level-3 prefixes c in {0,1,2}, odd
// c in {3,4} (s32/s42 redundant on odd, published by even). Per step:
// 4 LDS reads (b128 d0..d3, b32 d4, b32 da, b32 db) + 2 cndmask + ~31 FMA.
// Two register sets alternate; set loads sit after the consuming STEP so the
// prefetch distance is a full step (~78 issue-cyc) against ~120 cyc LDS latency.
__global__ __launch_bounds__(256) void sig_kernel(
    const float* __restrict__ x, const float* __restrict__ y,
    const float* __restrict__ sigma, float* __restrict__ acc,
    unsigned int* __restrict__ counter, float* __restrict__ out) {
  const int tid  = threadIdx.x;
  const int wave = tid >> 6;
  const int lane = tid & 63;
  const int b    = blockIdx.x * WPB + wave;        // sign block-uniform (BATCH%WPB==0)
  const bool isX = (b < BATCH);
  const int  p   = isX ? b : b - BATCH;
  const float* src = (isX ? x : y) + (size_t)p * (TLEN * CH);

  __shared__ __align__(16) float dxs[WPB][NROW * 8];   // row t: d0..d4, pad x3
  __shared__ float blockAcc[SIGDIM];
  __shared__ float red[4];
  __shared__ unsigned int lastFlag;

  for (int i = tid; i < SIGDIM; i += 256) blockAcc[i] = 0.f;

  // ---- fill increments (sigma folds linearly into x's non-time channels) ----
  float* mw = dxs[wave];
  if (lane < 8) mw[NSTEP * 8 + lane] = 0.f;            // zero pad row 127
  for (int i = lane; i < NSTEP * CH; i += 64) {
    int t = i / CH, c = i - CH * t;
    float v = src[i + CH] - src[i];
    if (isX && c > 0) v *= sigma[c - 1];
    mw[t * 8 + c] = v;
  }
  __syncthreads();

  // ---- per-lane ownership (loop-invariant) ----
  const int  ab  = (lane >> 1) < 25 ? (lane >> 1) : 24;  // clamp idle lanes 50..63
  const int  a_  = ab / 5, b_ = ab - 5 * a_;
  const bool odd = (lane & 1);
  const int  c0i = odd ? 3 : 0, c1i = odd ? 4 : 1;
  const bool act = (lane < 50);

  float s1a = 0.f, s2 = 0.f;
  float s30 = 0.f, s31 = 0.f, s32 = 0.f;
  float s40[5] = {0,0,0,0,0}, s41[5] = {0,0,0,0,0}, s42[5] = {0,0,0,0,0};

  auto STEP = [&](const float4& m, float d4, float da, float db) {
    const float d0 = m.x, d1 = m.y, d2 = m.z, d3 = m.w;
    const float dc0 = odd ? d3 : d0;                  // 1 cndmask (invariant mask)
    const float dc1 = odd ? d4 : d1;                  // 1 cndmask
    const float pa = s1a * (1.f / 6.f) + da * (1.f / 24.f);
    const float qa = s1a * 0.5f        + da * (1.f / 6.f);
    const float ra = s1a               + da * 0.5f;
    s1a += da;
    const float p2 = 0.5f * s2 + db * pa;
    const float q2 =        s2 + db * qa;
    s2 += db * ra;
    const float p30 = s30 + dc0 * p2;  s30 += dc0 * q2;
    const float p31 = s31 + dc1 * p2;  s31 += dc1 * q2;
    const float p32 = s32 + d2  * p2;  s32 += d2  * q2;
    s40[0] += d0 * p30; s40[1] += d1 * p30; s40[2] += d2 * p30; s40[3] += d3 * p30; s40[4] += d4 * p30;
    s41[0] += d0 * p31; s41[1] += d1 * p31; s41[2] += d2 * p31; s41[3] += d3 * p31; s41[4] += d4 * p31;
    s42[0] += d0 * p32; s42[1] += d1 * p32; s42[2] += d2 * p32; s42[3] += d3 * p32; s42[4] += d4 * p32;
  };

  // per-lane select streams
  const float* pa_ = mw + a_;
  const float* pb_ = mw + b_;

  // ---- 2-deep pipeline: set0 = even rows, set1 = odd rows ----
  float4 A0 = *(const float4*)(mw + 0);
  float  e0 = mw[4],  da0 = pa_[0], db0 = pb_[0];
  float4 A1 = *(const float4*)(mw + 8);
  float  e1 = mw[12], da1 = pa_[8], db1 = pb_[8];

  for (int g = 0; g < 63; ++g) {
    const int r0 = (2 * g + 2) * 8, r1 = (2 * g + 3) * 8;
    STEP(A0, e0, da0, db0);                           // row 2g
    A0 = *(const float4*)(mw + r0);
    e0 = mw[r0 + 4]; da0 = pa_[r0]; db0 = pb_[r0];
    STEP(A1, e1, da1, db1);                           // row 2g+1
    A1 = *(const float4*)(mw + r1);
    e1 = mw[r1 + 4]; da1 = pa_[r1]; db1 = pb_[r1];
  }
  STEP(A0, e0, da0, db0);                             // row 126 (set1 holds zero row 127)

  // ---- block-local accumulation in LDS ----
  if (act) {
    const int base3 = 30 + ab * 5;
    if ((lane % 10) == 0) atomicAdd(&blockAcc[lane / 10], s1a);
    if (!odd)             atomicAdd(&blockAcc[5 + ab], s2);
    atomicAdd(&blockAcc[base3 + c0i], s30);
    atomicAdd(&blockAcc[base3 + c1i], s31);
    if (!odd) atomicAdd(&blockAcc[base3 + 2], s32);
    const int b40 = 155 + (ab * 5 + c0i) * 5;
    const int b41 = 155 + (ab * 5 + c1i) * 5;
    const int b42 = 155 + (ab * 5 + 2) * 5;
    #pragma unroll
    for (int d = 0; d < 5; ++d) atomicAdd(&blockAcc[b40 + d], s40[d]);
    #pragma unroll
    for (int d = 0; d < 5; ++d) atomicAdd(&blockAcc[b41 + d], s41[d]);
    if (!odd) {
      #pragma unroll
      for (int d = 0; d < 5; ++d) atomicAdd(&blockAcc[b42 + d], s42[d]);
    }
  }
  __syncthreads();

  // ---- signed block -> global ----
  const float w = isX ? 1.0f : -1.0f;
  float* ap = acc + (size_t)(blockIdx.x & (KACC - 1)) * SIGDIM;
  for (int i = tid; i < SIGDIM; i += 256)
    atomicAdd(ap + i, w * blockAcc[i]);

  // ---- fused final reduction: last block computes ||u-v||^2 / B^2 ----
  __syncthreads();
  if (tid == 0) {
    __threadfence();
    unsigned int old = __hip_atomic_fetch_add(counter, 1u, __ATOMIC_ACQ_REL,
                                              __HIP_MEMORY_SCOPE_AGENT);
    lastFlag = (old == NBLK - 1) ? 1u : 0u;
  }
  __syncthreads();
  if (lastFlag) {
    float local = 0.f;
    for (int i = tid; i < SIGDIM; i += 256) {
      float v = 0.f;
      #pragma unroll
      for (int k = 0; k < KACC; ++k)
        v += __hip_atomic_load(&acc[(size_t)k * SIGDIM + i],
                               __ATOMIC_RELAXED, __HIP_MEMORY_SCOPE_AGENT);
      local += v * v;
    }
    #pragma unroll
    for (int off = 32; off > 0; off >>= 1) local += __shfl_down(local, off, 64);
    if ((tid & 63) == 0) red[tid >> 6] = local;
    __syncthreads();
    if (tid == 0)
      out[0] = (red[0] + red[1] + red[2] + red[3]) / (2048.0f * 2048.0f);
  }
}

extern "C" void kernel_launch(void* const* d_in, const int* in_sizes, int n_in,
                              void* d_out, int out_size, void* d_ws, size_t ws_size,
                              hipStream_t stream) {
  const float* x     = (const float*)d_in[0];
  const float* y     = (const float*)d_in[1];
  const float* sigma = (const float*)d_in[2];
  float* out = (float*)d_out;
  float* acc = (float*)d_ws;
  unsigned int* counter = (unsigned int*)((char*)d_ws + (size_t)KACC * SIGDIM * sizeof(float));

  hipMemsetAsync(d_ws, 0, (size_t)KACC * SIGDIM * sizeof(float) + 64, stream);
  sig_kernel<<<dim3(NBLK), dim3(256), 0, stream>>>(x, y, sigma, acc, counter, out);
}

// Round 7
// 112.954 us; speedup vs baseline: 1.2324x; 1.0930x over previous
//
#include <hip/hip_runtime.h>

#define BATCH  2048
#define TLEN   128
#define CH     5
#define NSTEP  127
#define NROW   128               // rows 0..126 real, row 127 zero (no-op pad)
#define SIGDIM 780               // 5 + 25 + 125 + 625
#define KACC   16                // global accumulator copies
#define PPB    8                 // paths per block (4 waves x 2 paths)
#define NBLK   ((2 * BATCH) / PPB)   // 512

// 2 paths per wave: half h = lane>>5 picks the path; sublane u = lane&31.
// Lane u<25 owns level-2 chain ab=u (a=u/5, b=u%5) with NO redundancy:
// s1a, s2, all 5 level-3 prefixes s3[c], all 25 level-4 accs s4[c][d] in regs.
// Per step: 4 broadcast LDS reads (b128 d0-d3, b32 d4, b32 da, b32 db) + 45 VALU
// serving TWO path-steps. Unroll-8 w/ immediate ds offsets (read2 merging).
__global__ __launch_bounds__(256, 2) void sig_kernel(
    const float* __restrict__ x, const float* __restrict__ y,
    const float* __restrict__ sigma, float* __restrict__ acc,
    unsigned int* __restrict__ counter, float* __restrict__ out) {
  const int tid  = threadIdx.x;
  const int wave = tid >> 6;
  const int lane = tid & 63;
  const int h    = lane >> 5;          // which path of this wave
  const int u    = lane & 31;          // sublane within half
  const bool isX = (blockIdx.x < NBLK / 2);
  const int pbase = (isX ? blockIdx.x : blockIdx.x - NBLK / 2) * PPB;
  const int path  = pbase + wave * 2 + h;
  const float* src = (isX ? x : y) + (size_t)path * (TLEN * CH);

  __shared__ __align__(16) float dxs[PPB][NROW * 8];   // row t: d0..d4, pad x3 (32 KB)
  __shared__ float blockAcc[SIGDIM];
  __shared__ float red[4];
  __shared__ unsigned int lastFlag;

  for (int i = tid; i < SIGDIM; i += 256) blockAcc[i] = 0.f;

  // ---- fill increments: each 32-lane half fills its own path ----
  float* row = dxs[wave * 2 + h];
  if (u < 8) row[NSTEP * 8 + u] = 0.f;                 // zero row 127
  for (int i = u; i < NSTEP * CH; i += 32) {
    int t = i / CH, c = i - CH * t;
    float v = src[i + CH] - src[i];
    if (isX && c > 0) v *= sigma[c - 1];
    row[t * 8 + c] = v;
  }
  __syncthreads();

  // ---- ownership ----
  const int  uc = u < 25 ? u : 24;                     // clamp idle sublanes 25..31
  const int  a_ = uc / 5, b_ = uc - 5 * a_;
  const bool act = (u < 25);

  float s1a = 0.f, s2 = 0.f;
  float s3[5] = {0,0,0,0,0};
  float s4[5][5] = {{0,0,0,0,0},{0,0,0,0,0},{0,0,0,0,0},{0,0,0,0,0},{0,0,0,0,0}};

  const float* pa_ = row + a_;                         // per-lane da stream
  const float* pb_ = row + b_;                         // per-lane db stream

  // ---- main loop: 16 groups x 8 rows (row 127 = zero no-op) ----
  for (int g = 0; g < 16; ++g) {
    const float* rg = row + g * 64;
    const float* ra = pa_ + g * 64;
    const float* rb = pb_ + g * 64;
    #pragma unroll
    for (int k = 0; k < 8; ++k) {
      const float4 m = *(const float4*)(rg + k * 8);
      const float d0 = m.x, d1 = m.y, d2 = m.z, d3 = m.w;
      const float d4 = rg[k * 8 + 4];
      const float da = ra[k * 8];
      const float db = rb[k * 8];
      // level-1 helpers (old s1a)
      const float pa = s1a * (1.f / 6.f) + da * (1.f / 24.f);
      const float qa = s1a * 0.5f        + da * (1.f / 6.f);
      const float ra_ = s1a              + da * 0.5f;
      s1a += da;
      // level-2 (old s2)
      const float p2 = 0.5f * s2 + db * pa;
      const float q2 =        s2 + db * qa;
      s2 += db * ra_;
      // level-3/4: all 5 prefixes of this chain
      #pragma unroll
      for (int c = 0; c < 5; ++c) {
        const float dc = c == 0 ? d0 : c == 1 ? d1 : c == 2 ? d2 : c == 3 ? d3 : d4;
        const float p3 = s3[c] + dc * p2;
        s3[c] += dc * q2;
        s4[c][0] += d0 * p3; s4[c][1] += d1 * p3; s4[c][2] += d2 * p3;
        s4[c][3] += d3 * p3; s4[c][4] += d4 * p3;
      }
    }
  }

  // ---- block-local accumulation (8 paths -> blockAcc via LDS atomics) ----
  if (act) {
    if (b_ == 0) atomicAdd(&blockAcc[a_], s1a);
    atomicAdd(&blockAcc[5 + uc], s2);
    #pragma unroll
    for (int c = 0; c < 5; ++c) {
      atomicAdd(&blockAcc[30 + uc * 5 + c], s3[c]);
      #pragma unroll
      for (int d = 0; d < 5; ++d)
        atomicAdd(&blockAcc[155 + (uc * 5 + c) * 5 + d], s4[c][d]);
    }
  }
  __syncthreads();

  // ---- signed block -> global ----
  const float w = isX ? 1.0f : -1.0f;
  float* ap = acc + (size_t)(blockIdx.x & (KACC - 1)) * SIGDIM;
  for (int i = tid; i < SIGDIM; i += 256)
    atomicAdd(ap + i, w * blockAcc[i]);

  // ---- fused final reduction: last block computes ||u-v||^2 / B^2 ----
  __syncthreads();
  if (tid == 0) {
    __threadfence();
    unsigned int old = __hip_atomic_fetch_add(counter, 1u, __ATOMIC_ACQ_REL,
                                              __HIP_MEMORY_SCOPE_AGENT);
    lastFlag = (old == NBLK - 1) ? 1u : 0u;
  }
  __syncthreads();
  if (lastFlag) {
    float local = 0.f;
    for (int i = tid; i < SIGDIM; i += 256) {
      float v = 0.f;
      #pragma unroll
      for (int k = 0; k < KACC; ++k)
        v += __hip_atomic_load(&acc[(size_t)k * SIGDIM + i],
                               __ATOMIC_RELAXED, __HIP_MEMORY_SCOPE_AGENT);
      local += v * v;
    }
    #pragma unroll
    for (int off = 32; off > 0; off >>= 1) local += __shfl_down(local, off, 64);
    if ((tid & 63) == 0) red[tid >> 6] = local;
    __syncthreads();
    if (tid == 0)
      out[0] = (red[0] + red[1] + red[2] + red[3]) / (2048.0f * 2048.0f);
  }
}

extern "C" void kernel_launch(void* const* d_in, const int* in_sizes, int n_in,
                              void* d_out, int out_size, void* d_ws, size_t ws_size,
                              hipStream_t stream) {
  const float* x     = (const float*)d_in[0];
  const float* y     = (const float*)d_in[1];
  const float* sigma = (const float*)d_in[2];
  float* out = (float*)d_out;
  float* acc = (float*)d_ws;
  unsigned int* counter = (unsigned int*)((char*)d_ws + (size_t)KACC * SIGDIM * sizeof(float));

  hipMemsetAsync(d_ws, 0, (size_t)KACC * SIGDIM * sizeof(float) + 64, stream);
  sig_kernel<<<dim3(NBLK), dim3(256), 0, stream>>>(x, y, sigma, acc, counter, out);
}

// Round 8
// 110.795 us; speedup vs baseline: 1.2565x; 1.0195x over previous
//
#include <hip/hip_runtime.h>

#define BATCH  2048
#define TLEN   128
#define CH     5
#define SIGDIM 780               // 5 + 25 + 125 + 625
#define KACC   16                // global accumulator copies
#define PPB    4                 // paths per block (4 waves; wave w = path w, halves = time segs)
#define NBLK   ((2 * BATCH) / PPB)   // 1024
#define SEGR   64                // rows per segment (seg1: 63 real + 1 zero pad)

// R7 mapping + time-split for occupancy. Wave w handles path (pbase+w):
//   half h (lanes h*32..h*32+31) runs time-segment h (64 steps).
// Lane u<25 owns chain ab=u: s1a, s2, s3[5], s4[25] in regs (no redundancy).
// Per wave-step: 4 broadcast LDS reads + ~46 VALU serving two segment-steps.
// After the loop, half 1 publishes its segment sig to LDS; half 0 Chen-combines
// (S = SL (x) SR; L in registers, R from LDS) and accumulates into blockAcc.
__global__ __launch_bounds__(256, 4) void sig_kernel(
    const float* __restrict__ x, const float* __restrict__ y,
    const float* __restrict__ sigma, float* __restrict__ acc,
    unsigned int* __restrict__ counter, float* __restrict__ out) {
  const int tid  = threadIdx.x;
  const int wave = tid >> 6;
  const int lane = tid & 63;
  const int h    = lane >> 5;          // time segment
  const int u    = lane & 31;          // sublane within half
  const bool isX = (blockIdx.x < NBLK / 2);
  const int pbase = (isX ? blockIdx.x : blockIdx.x - NBLK / 2) * PPB;
  const int path  = pbase + wave;
  const float* src = (isX ? x : y) + (size_t)path * (TLEN * CH) + h * (SEGR * CH);

  __shared__ __align__(16) float buf[2 * PPB][784];  // [wave*2+h]: increments, then seg-1 sig
  __shared__ float blockAcc[SIGDIM];
  __shared__ float red[4];
  __shared__ unsigned int lastFlag;

  for (int i = tid; i < SIGDIM; i += 256) blockAcc[i] = 0.f;

  // ---- fill increments: rows t*8+c; seg1 has 63 real rows + zero row 63 ----
  float* bw = buf[wave * 2 + h];
  if (h == 1 && u < 8) bw[63 * 8 + u] = 0.f;
  const int lim = h ? 63 * CH : 64 * CH;
  for (int i = u; i < lim; i += 32) {
    int t = i / CH, c = i - CH * t;
    float v = src[i + CH] - src[i];
    if (isX && c > 0) v *= sigma[c - 1];
    bw[t * 8 + c] = v;
  }
  __syncthreads();

  // ---- ownership ----
  const int  uc = u < 25 ? u : 24;     // clamp idle sublanes 25..31
  const int  a_ = uc / 5, b_ = uc - 5 * a_;
  const bool act = (u < 25);

  float s1a = 0.f, s2 = 0.f;
  float s3[5] = {0,0,0,0,0};
  float s4[5][5] = {{0,0,0,0,0},{0,0,0,0,0},{0,0,0,0,0},{0,0,0,0,0},{0,0,0,0,0}};

  const float* pa_ = bw + a_;
  const float* pb_ = bw + b_;

  // ---- main loop: 8 groups x 8 rows = 64 steps (seg1 row 63 = zero no-op) ----
  for (int g = 0; g < 8; ++g) {
    const float* rg = bw + g * 64;
    const float* ra = pa_ + g * 64;
    const float* rb = pb_ + g * 64;
    #pragma unroll
    for (int k = 0; k < 8; ++k) {
      const float4 m = *(const float4*)(rg + k * 8);
      const float d0 = m.x, d1 = m.y, d2 = m.z, d3 = m.w;
      const float d4 = rg[k * 8 + 4];
      const float da = ra[k * 8];
      const float db = rb[k * 8];
      const float pa = s1a * (1.f / 6.f) + da * (1.f / 24.f);
      const float qa = s1a * 0.5f        + da * (1.f / 6.f);
      const float rr = s1a               + da * 0.5f;
      s1a += da;
      const float p2 = 0.5f * s2 + db * pa;
      const float q2 =        s2 + db * qa;
      s2 += db * rr;
      #pragma unroll
      for (int c = 0; c < 5; ++c) {
        const float dc = c == 0 ? d0 : c == 1 ? d1 : c == 2 ? d2 : c == 3 ? d3 : d4;
        const float p3 = s3[c] + dc * p2;
        s3[c] += dc * q2;
        s4[c][0] += d0 * p3; s4[c][1] += d1 * p3; s4[c][2] += d2 * p3;
        s4[c][3] += d3 * p3; s4[c][4] += d4 * p3;
      }
    }
  }

  // ---- half 1 publishes its segment signature (increments are dead) ----
  if (h == 1 && act) {
    float* sg = bw;
    if (b_ == 0) sg[a_] = s1a;
    sg[5 + uc] = s2;
    #pragma unroll
    for (int c = 0; c < 5; ++c) {
      sg[30 + uc * 5 + c] = s3[c];
      #pragma unroll
      for (int d = 0; d < 5; ++d) sg[155 + (uc * 5 + c) * 5 + d] = s4[c][d];
    }
  }
  __syncthreads();

  // ---- half 0: Chen combine S = SL (x) SR, L in regs, R = buf[wave*2+1] ----
  if (h == 0 && act) {
    const float* R = buf[wave * 2 + 1];
    const float o1 = s1a + R[a_];
    const float o2 = s2 + s1a * R[b_] + R[5 + uc];
    if (b_ == 0) atomicAdd(&blockAcc[a_], o1);
    atomicAdd(&blockAcc[5 + uc], o2);
    #pragma unroll
    for (int c = 0; c < 5; ++c) {
      const float o3 = s3[c] + s2 * R[c] + s1a * R[5 + b_ * 5 + c] + R[30 + uc * 5 + c];
      atomicAdd(&blockAcc[30 + uc * 5 + c], o3);
      #pragma unroll
      for (int d = 0; d < 5; ++d) {
        const float o4 = s4[c][d] + s3[c] * R[d] + s2 * R[5 + c * 5 + d]
                       + s1a * R[30 + (b_ * 5 + c) * 5 + d]
                       + R[155 + (uc * 5 + c) * 5 + d];
        atomicAdd(&blockAcc[155 + (uc * 5 + c) * 5 + d], o4);
      }
    }
  }
  __syncthreads();

  // ---- signed block -> global ----
  const float w = isX ? 1.0f : -1.0f;
  float* ap = acc + (size_t)(blockIdx.x & (KACC - 1)) * SIGDIM;
  for (int i = tid; i < SIGDIM; i += 256)
    atomicAdd(ap + i, w * blockAcc[i]);

  // ---- fused final reduction: last block computes ||u-v||^2 / B^2 ----
  __syncthreads();
  if (tid == 0) {
    __threadfence();
    unsigned int old = __hip_atomic_fetch_add(counter, 1u, __ATOMIC_ACQ_REL,
                                              __HIP_MEMORY_SCOPE_AGENT);
    lastFlag = (old == NBLK - 1) ? 1u : 0u;
  }
  __syncthreads();
  if (lastFlag) {
    float local = 0.f;
    for (int i = tid; i < SIGDIM; i += 256) {
      float v = 0.f;
      #pragma unroll
      for (int k = 0; k < KACC; ++k)
        v += __hip_atomic_load(&acc[(size_t)k * SIGDIM + i],
                               __ATOMIC_RELAXED, __HIP_MEMORY_SCOPE_AGENT);
      local += v * v;
    }
    #pragma unroll
    for (int off = 32; off > 0; off >>= 1) local += __shfl_down(local, off, 64);
    if ((tid & 63) == 0) red[tid >> 6] = local;
    __syncthreads();
    if (tid == 0)
      out[0] = (red[0] + red[1] + red[2] + red[3]) / (2048.0f * 2048.0f);
  }
}

extern "C" void kernel_launch(void* const* d_in, const int* in_sizes, int n_in,
                              void* d_out, int out_size, void* d_ws, size_t ws_size,
                              hipStream_t stream) {
  const float* x     = (const float*)d_in[0];
  const float* y     = (const float*)d_in[1];
  const float* sigma = (const float*)d_in[2];
  float* out = (float*)d_out;
  float* acc = (float*)d_ws;
  unsigned int* counter = (unsigned int*)((char*)d_ws + (size_t)KACC * SIGDIM * sizeof(float));

  hipMemsetAsync(d_ws, 0, (size_t)KACC * SIGDIM * sizeof(float) + 64, stream);
  sig_kernel<<<dim3(NBLK), dim3(256), 0, stream>>>(x, y, sigma, acc, counter, out);
}